// Round 23
// baseline (321.859 us; speedup 1.0000x reference)
//
#include <hip/hip_runtime.h>

// ---------------------------------------------------------------------------
// GraphSAGE (mean) x3: h' = relu(mean_agg(h)@Wl + h@Wr + b).
// R23: R22 base + burst-32 combine: each 4-lane half issues 16-deep clamped
//      gathers (32 loads in flight per node) so 96% of nodes (deg<=32)
//      finish in ONE latency round-trip (wave-max trips 2.1 -> ~1.05).
//      csr software-pipeline dropped (proven null; saves VGPR).
//   Zl,Zr stored [8][N][32]: 3.2MB panel fits one XCD L2; slice = bid&7.
// ---------------------------------------------------------------------------

typedef __attribute__((ext_vector_type(8))) _Float16 f16x8;
typedef __attribute__((ext_vector_type(4))) float f32x4;

// ------------------------------- CSR build --------------------------------
__global__ void count_deg_kernel(const int* __restrict__ dst,
                                 int* __restrict__ deg, int E) {
    int i = (blockIdx.x * blockDim.x + threadIdx.x) * 2;
    if (i + 1 < E) {
        int2 d = *(const int2*)&dst[i];
        atomicAdd(&deg[d.x], 1);
        atomicAdd(&deg[d.y], 1);
    } else if (i < E) {
        atomicAdd(&deg[dst[i]], 1);
    }
}

__device__ __forceinline__ int block_excl_scan_256(int v, int tid) {
    int lane = tid & 63, w = tid >> 6;
    int x = v;
#pragma unroll
    for (int off = 1; off < 64; off <<= 1) {
        int y = __shfl_up(x, off);
        if (lane >= off) x += y;
    }
    __shared__ int wsum[4], woff[4];
    if (lane == 63) wsum[w] = x;
    __syncthreads();
    if (tid == 0) {
        int a = 0;
#pragma unroll
        for (int i = 0; i < 4; ++i) { woff[i] = a; a += wsum[i]; }
    }
    __syncthreads();
    return woff[w] + x - v;
}

__global__ void scan_phase1(const int* __restrict__ deg,
                            int* __restrict__ partial, int n) {
    int base = blockIdx.x * 1024;
    int s = 0;
    for (int i = threadIdx.x; i < 1024; i += 256) {
        int idx = base + i;
        s += (idx < n) ? deg[idx] : 0;
    }
    __shared__ int ws4[4];
    int lane = threadIdx.x & 63, w = threadIdx.x >> 6;
#pragma unroll
    for (int off = 32; off; off >>= 1) s += __shfl_down(s, off);
    if (lane == 0) ws4[w] = s;
    __syncthreads();
    if (threadIdx.x == 0)
        partial[blockIdx.x] = ws4[0] + ws4[1] + ws4[2] + ws4[3];
}

__global__ void scan_phase2(int* __restrict__ partial, int nb,
                            int* __restrict__ rowptr, int n, int E) {
    int tid = threadIdx.x;
    int v = (tid < nb) ? partial[tid] : 0;
    int ex = block_excl_scan_256(v, tid);
    if (tid < nb) partial[tid] = ex;
    if (tid == 0) rowptr[n] = E;
}

__global__ void scan_phase3(const int* __restrict__ deg,
                            const int* __restrict__ partial,
                            int* __restrict__ rowptr, int* __restrict__ cursor,
                            float* __restrict__ inv_deg, int n) {
    int base = blockIdx.x * 1024 + threadIdx.x * 4;
    int d[4];
#pragma unroll
    for (int j = 0; j < 4; ++j) {
        int idx = base + j;
        d[j] = (idx < n) ? deg[idx] : 0;
    }
    int tsum = d[0] + d[1] + d[2] + d[3];
    int ex = block_excl_scan_256(tsum, threadIdx.x);
    int run = partial[blockIdx.x] + ex;
#pragma unroll
    for (int j = 0; j < 4; ++j) {
        int idx = base + j;
        if (idx < n) {
            rowptr[idx] = run;
            cursor[idx] = run;
            inv_deg[idx] = 1.0f / (float)max(d[j], 1);
        }
        run += d[j];
    }
}

// XCD-partitioned fill: dst range g = bid&7 (round-robin -> XCD g).
__global__ void fill_csr_xcd_kernel(const int* __restrict__ src,
                                    const int* __restrict__ dst,
                                    int* __restrict__ cursor,
                                    int* __restrict__ csr_src, int E, int n) {
    const int g = blockIdx.x & 7;
    const int lo = g * (n >> 3);
    const int hi = (g == 7) ? n : lo + (n >> 3);
    int i = ((blockIdx.x >> 3) * 256 + threadIdx.x) * 2;
    if (i + 1 < E) {
        int2 d = *(const int2*)&dst[i];
        if ((d.x >= lo && d.x < hi) || (d.y >= lo && d.y < hi)) {
            int2 s = *(const int2*)&src[i];
            if (d.x >= lo && d.x < hi) {
                int p = atomicAdd(&cursor[d.x], 1);
                csr_src[p] = s.x;
            }
            if (d.y >= lo && d.y < hi) {
                int p = atomicAdd(&cursor[d.y], 1);
                csr_src[p] = s.y;
            }
        }
    } else if (i < E) {
        int d = dst[i];
        if (d >= lo && d < hi) {
            int p = atomicAdd(&cursor[d], 1);
            csr_src[p] = src[i];
        }
    }
}

// ----------------- W -> fp16 fragment order (+ zero deg) -------------------
// per (layer,source): [k0chunk(8)][tile(16)][g(4)][col(16)][j(8)]
__global__ void presplit_w_kernel(const float* __restrict__ Wl,
                                  const float* __restrict__ Wr,
                                  _Float16* __restrict__ Wf,
                                  int* __restrict__ deg, int N, int total) {
    int idx = blockIdx.x * blockDim.x + threadIdx.x;
    if (idx < N) deg[idx] = 0;
    if (idx >= total) return;
    int l = idx >> 17;
    int rem = idx & 131071;
    int s = rem >> 16;
    int kc = rem & 65535;
    int k = kc >> 8, c = kc & 255;
    const float* W = s ? Wr : Wl;
    float w = W[((size_t)l * 256 + k) * 256 + c];
    int k0c = k >> 5, g = (k >> 3) & 3, j = k & 7;
    int tile = c >> 4, col = c & 15;
    int fi = (l * 2 + s) * 65536 + k0c * 8192 + ((tile * 4 + g) * 16 + col) * 8 + j;
    Wf[fi] = (_Float16)w;
}

// --------------------------- dual GEMM (fp32 or fp16 A) --------------------
// 64-row block, 8 waves: wave w -> ALL 64 rows x cols w*32..w*32+31
// (4 row-tiles x 2 col-tiles). W prefetched TWO k0-steps ahead (3-buffer
// static rotation; fully unrolled so all indices are compile-time).
// A: x fp32 row-major (layer 0) or h fp16 panel-major [8][M][32].
// OUTPUT PANEL-MAJOR: z[p][row][off], p=col>>5.
__global__ __launch_bounds__(512) void gemm_dual_kernel(
    const float* __restrict__ xsrc, const _Float16* __restrict__ hsrc,
    int f32src, _Float16* __restrict__ zl, _Float16* __restrict__ zr,
    const _Float16* __restrict__ Wf_l, const float* __restrict__ bias, int M) {
    __shared__ __align__(16) _Float16 Ah[32][65][8];
    const int tid = threadIdx.x;
    const int r0 = blockIdx.x * 64;
    const int wave = tid >> 6, lane = tid & 63;
    const int l15 = lane & 15, lg = lane >> 4;
    const int wc = wave * 32;
    const int tg0 = wc >> 4;               // = wave*2
    const _Float16* wbase = Wf_l + (lg * 16 + l15) * 8;

    // steps 0 and 1 W prefetch BEFORE staging (latency hides under LDS fill)
    f16x8 wl[3][2], wr[3][2];
#pragma unroll
    for (int s = 0; s < 2; ++s)
#pragma unroll
        for (int t = 0; t < 2; ++t) {
            wl[s][t] = *(const f16x8*)&wbase[s * 8192 + (tg0 + t) * 512];
            wr[s][t] = *(const f16x8*)&wbase[s * 8192 + 65536 + (tg0 + t) * 512];
        }

    // ---- stage A stripe (64x256) ----
#pragma unroll
    for (int i = 0; i < 4; ++i) {
        int idx = i * 512 + tid;        // 0..2047
        int row = idx >> 5, g = idx & 31;
        int grow = r0 + row;
        f16x8 v = (f16x8)(_Float16)0;
        if (grow < M) {
            if (f32src) {
                const float4* p =
                    (const float4*)&xsrc[(size_t)grow * 256 + g * 8];
                float4 v0 = p[0], v1 = p[1];
                v[0] = (_Float16)v0.x; v[1] = (_Float16)v0.y;
                v[2] = (_Float16)v0.z; v[3] = (_Float16)v0.w;
                v[4] = (_Float16)v1.x; v[5] = (_Float16)v1.y;
                v[6] = (_Float16)v1.z; v[7] = (_Float16)v1.w;
            } else {
                int p = g >> 2, off = (g & 3) * 8;   // panel-major h
                v = *(const f16x8*)&hsrc[((size_t)p * M + grow) * 32 + off];
            }
        }
        *(f16x8*)&Ah[g][row][0] = v;
    }
    __syncthreads();

    // ---- MFMA main loop (W prefetched two steps ahead) ----
    f32x4 accl[4][2], accr[4][2];
#pragma unroll
    for (int rt = 0; rt < 4; ++rt)
#pragma unroll
        for (int t = 0; t < 2; ++t) {
            accl[rt][t] = (f32x4)(0.0f);
            accr[rt][t] = (f32x4)(0.0f);
        }

#pragma unroll
    for (int s = 0; s < 8; ++s) {
        if (s < 6) {
            const _Float16* wn = wbase + (s + 2) * 8192;
#pragma unroll
            for (int t = 0; t < 2; ++t) {
                wl[(s + 2) % 3][t] = *(const f16x8*)&wn[(tg0 + t) * 512];
                wr[(s + 2) % 3][t] =
                    *(const f16x8*)&wn[65536 + (tg0 + t) * 512];
            }
        }
        f16x8 a[4];
#pragma unroll
        for (int rt = 0; rt < 4; ++rt)
            a[rt] = *(const f16x8*)&Ah[s * 4 + lg][rt * 16 + l15][0];
#pragma unroll
        for (int t = 0; t < 2; ++t) {
#pragma unroll
            for (int rt = 0; rt < 4; ++rt) {
                accl[rt][t] = __builtin_amdgcn_mfma_f32_16x16x32_f16(
                    a[rt], wl[s % 3][t], accl[rt][t], 0, 0, 0);
                accr[rt][t] = __builtin_amdgcn_mfma_f32_16x16x32_f16(
                    a[rt], wr[s % 3][t], accr[rt][t], 0, 0, 0);
            }
        }
    }

    float bv[2];
#pragma unroll
    for (int t = 0; t < 2; ++t) bv[t] = bias[wc + t * 16 + l15];
#pragma unroll
    for (int rt = 0; rt < 4; ++rt) {
#pragma unroll
        for (int r = 0; r < 4; ++r) {
            int grow = r0 + rt * 16 + lg * 4 + r;
            if (grow >= M) continue;
#pragma unroll
            for (int t = 0; t < 2; ++t) {
                int col = wc + t * 16 + l15;
                int p = col >> 5, off = col & 31;
                size_t zi = ((size_t)p * M + grow) * 32 + off;
                zl[zi] = (_Float16)accl[rt][t][r];
                zr[zi] = (_Float16)(accr[rt][t][r] + bv[t]);
            }
        }
    }
}

// ------------------- panel-major sliced combine (burst-32) -----------------
// grid = 8 slices x ceil(n/32); slice = bid&7 -> XCD bid%8 (panel in L2).
// 8 lanes per node: two 4-lane halves each issue 16-deep clamped gathers
// (32 loads in flight per node -> deg<=32 nodes finish in ONE trip).
// SGPR base + 32-bit offsets (saddr form). Dual-chain packed fp16
// accumulation; clamped duplicates corrected by closed-form subtract.
// mode 0: relu -> fp16 PANEL-MAJOR h. mode 1: fp32 row-major out.
__global__ __launch_bounds__(256) void combine_panel_kernel(
    const _Float16* __restrict__ zl, const _Float16* __restrict__ zr,
    const int* __restrict__ rowptr, const int* __restrict__ csr_src,
    const float* __restrict__ inv_deg, _Float16* __restrict__ hout,
    float* __restrict__ fout, int n, int mode) {
    const int slice = blockIdx.x & 7;
    const int chunk = blockIdx.x >> 3;
    const int grp = threadIdx.x >> 3;     // 0..31
    const int sub = threadIdx.x & 7;
    const int pair = sub >> 2;            // 0 or 1
    const int l4 = sub & 3;
    // block-uniform bases (SGPR); per-lane 32-bit byte offsets
    const char* zl_s = (const char*)(zl + (size_t)slice * n * 32);
    const char* zr_s = (const char*)(zr + (size_t)slice * n * 32);
    const unsigned lb = (unsigned)l4 * 16;

    int v = chunk * 32 + grp;
    if (v >= n) return;
    int beg = rowptr[v], end = rowptr[v + 1];
    float sc = inv_deg[v];
    f16x8 zp = *(const f16x8*)(zr_s + (((unsigned)v << 6) + lb));
    float o[8];
    if (beg < end) {
        f16x8 acc0 = (f16x8)(_Float16)0, acc1 = (f16x8)(_Float16)0;
        for (int e = beg; e < end; e += 32) {
            int e0 = e + pair * 16;
            f16x8 t[16];
#pragma unroll
            for (int k = 0; k < 16; ++k) {
                int u = csr_src[min(e0 + k, end - 1)];
                t[k] = *(const f16x8*)(zl_s + (((unsigned)u << 6) + lb));
            }
#pragma unroll
            for (int k = 0; k < 8; ++k) {
                acc0 += t[k];              // v_pk_add_f16, two chains for ILP
                acc1 += t[k + 8];
            }
        }
        // overcount fixup: last trip's clamped duplicates of edge end-1
        int d = end - beg;
        int T = (d + 31) >> 5;
        int rem = d - ((T - 1) << 5);                 // 1..32
        int valid = pair ? max(rem - 16, 0) : min(rem, 16);
        float inval = (float)(16 - valid);
        int ulast = csr_src[end - 1];
        f16x8 tl = *(const f16x8*)(zl_s + (((unsigned)ulast << 6) + lb));
#pragma unroll
        for (int j = 0; j < 8; ++j)
            o[j] = (float)acc0[j] + (float)acc1[j] - inval * (float)tl[j];
    } else {
#pragma unroll
        for (int j = 0; j < 8; ++j) o[j] = 0.0f;
    }
#pragma unroll
    for (int j = 0; j < 8; ++j) o[j] += __shfl_xor(o[j], 4);
    if (pair == 0) {
#pragma unroll
        for (int j = 0; j < 8; ++j) o[j] = o[j] * sc + (float)zp[j];
        if (mode == 0) {
            f16x8 hv;
#pragma unroll
            for (int j = 0; j < 8; ++j) hv[j] = (_Float16)fmaxf(o[j], 0.0f);
            *(f16x8*)&hout[((size_t)slice * n + v) * 32 + l4 * 8] = hv;
        } else {
            int cbase = slice * 32 + l4 * 8;
            float4* op = (float4*)&fout[(size_t)v * 256 + cbase];
            op[0] = make_float4(o[0], o[1], o[2], o[3]);
            op[1] = make_float4(o[4], o[5], o[6], o[7]);
        }
    }
}

// --------------------------------- launch ---------------------------------
extern "C" void kernel_launch(void* const* d_in, const int* in_sizes, int n_in,
                              void* d_out, int out_size, void* d_ws, size_t ws_size,
                              hipStream_t stream) {
    const int D = 256;
    const int N = in_sizes[0] / D;
    const int E = in_sizes[1] / 2;
    const int L = in_sizes[2] / (D * D);

    const float* x  = (const float*)d_in[0];
    const int*   ei = (const int*)d_in[1];
    const float* Wl = (const float*)d_in[2];
    const float* Wr = (const float*)d_in[3];
    const float* b  = (const float*)d_in[4];
    const int* src = ei;
    const int* dst = ei + E;

    size_t off = 0;
    auto alloc = [&](size_t bytes) {
        void* p = (char*)d_ws + off;
        off += (bytes + 255) & ~(size_t)255;
        return p;
    };
    int*   deg     = (int*)alloc((size_t)N * 4);
    int*   rowptr  = (int*)alloc((size_t)(N + 1) * 4);
    int*   cursor  = (int*)alloc((size_t)N * 4);
    float* inv_deg = (float*)alloc((size_t)N * 4);
    int*   csr_src = (int*)alloc((size_t)E * 4);
    int*   partial = (int*)alloc(256 * 4);
    _Float16* zlP  = (_Float16*)alloc((size_t)N * D * 2);  // pair P (panel-major)
    _Float16* zrP  = (_Float16*)alloc((size_t)N * D * 2);
    _Float16* hbuf = (_Float16*)alloc((size_t)N * D * 2);  // h (panel-major)
    _Float16* Wf   = (_Float16*)alloc((size_t)L * 2 * 65536 * 2);
    (void)ws_size;

    // pair Q packed into d_out (panel-major fp16); C2 overwrites with fp32
    _Float16* zlQ = (_Float16*)d_out;
    _Float16* zrQ = zlQ + (size_t)N * D;
    float* outf = (float*)d_out;

    const int scan_blocks = (N + 1023) / 1024;

    // W -> fp16 fragment order (also zeroes deg)
    int wtotal = L * 2 * 65536;
    hipLaunchKernelGGL(presplit_w_kernel, dim3((wtotal + 255) / 256), dim3(256),
                       0, stream, Wl, Wr, Wf, deg, N, wtotal);

    // CSR build
    hipLaunchKernelGGL(count_deg_kernel, dim3((E / 2 + 255) / 256), dim3(256),
                       0, stream, dst, deg, E);
    hipLaunchKernelGGL(scan_phase1, dim3(scan_blocks), dim3(256), 0, stream,
                       deg, partial, N);
    hipLaunchKernelGGL(scan_phase2, dim3(1), dim3(256), 0, stream,
                       partial, scan_blocks, rowptr, N, E);
    hipLaunchKernelGGL(scan_phase3, dim3(scan_blocks), dim3(256), 0, stream,
                       deg, partial, rowptr, cursor, inv_deg, N);
    const int fill_chunks = (E / 2 + 255) / 256;
    hipLaunchKernelGGL(fill_csr_xcd_kernel, dim3(8 * fill_chunks), dim3(256),
                       0, stream, src, dst, cursor, csr_src, E, N);

    const int gemm_blocks = (N + 63) / 64;
    const int comb_blocks = 8 * ((N + 31) / 32);

    // L0: x -> P ; combine P -> h
    hipLaunchKernelGGL(gemm_dual_kernel, dim3(gemm_blocks), dim3(512), 0,
                       stream, x, (const _Float16*)nullptr, 1, zlP, zrP,
                       Wf, b, N);
    hipLaunchKernelGGL(combine_panel_kernel, dim3(comb_blocks), dim3(256), 0,
                       stream, zlP, zrP, rowptr, csr_src, inv_deg,
                       hbuf, outf, N, 0);
    // L1: h -> Q (d_out) ; combine Q -> h
    hipLaunchKernelGGL(gemm_dual_kernel, dim3(gemm_blocks), dim3(512), 0,
                       stream, (const float*)nullptr, hbuf, 0, zlQ, zrQ,
                       Wf + 131072, b + D, N);
    hipLaunchKernelGGL(combine_panel_kernel, dim3(comb_blocks), dim3(256), 0,
                       stream, zlQ, zrQ, rowptr, csr_src, inv_deg,
                       hbuf, outf, N, 0);
    // L2: h -> P ; final combine P -> d_out fp32
    hipLaunchKernelGGL(gemm_dual_kernel, dim3(gemm_blocks), dim3(512), 0,
                       stream, (const float*)nullptr, hbuf, 0, zlP, zrP,
                       Wf + 262144, b + 2 * D, N);
    hipLaunchKernelGGL(combine_panel_kernel, dim3(comb_blocks), dim3(256), 0,
                       stream, zlP, zrP, rowptr, csr_src, inv_deg,
                       hbuf, outf, N, 1);
}

// Round 24
// 318.417 us; speedup vs baseline: 1.0108x; 1.0108x over previous
//
#include <hip/hip_runtime.h>

// ---------------------------------------------------------------------------
// GraphSAGE (mean) x3: h' = relu(mean_agg(h)@Wl + h@Wr + b).
// R24 = R22 (best measured config, 318.9us):
//  - linearity split: Zl=h@Wl, Zr=h@Wr+b (dual GEMM), combine gathers Zl.
//  - Zl,Zr panel-major [8][N][32]; slice=bid&7 pins each 3.2MB panel to one
//    XCD's L2 (fill 191->65MB).
//  - combine: 8 lanes/node, two 4-lane halves, 8-deep clamped bursts, csr
//    prefetch, SGPR-base+32bit-offset gathers, packed fp16 dual-chain accum,
//    closed-form overcount fixup. (Established L2-random floor ~55us.)
//  - GEMM: 64-row blocks, 8 waves x (64 rows x 32 cols), 2-deep W prefetch.
//  - XCD-partitioned CSR fill; multi-block scans.
// ---------------------------------------------------------------------------

typedef __attribute__((ext_vector_type(8))) _Float16 f16x8;
typedef __attribute__((ext_vector_type(4))) float f32x4;

// ------------------------------- CSR build --------------------------------
__global__ void count_deg_kernel(const int* __restrict__ dst,
                                 int* __restrict__ deg, int E) {
    int i = (blockIdx.x * blockDim.x + threadIdx.x) * 2;
    if (i + 1 < E) {
        int2 d = *(const int2*)&dst[i];
        atomicAdd(&deg[d.x], 1);
        atomicAdd(&deg[d.y], 1);
    } else if (i < E) {
        atomicAdd(&deg[dst[i]], 1);
    }
}

__device__ __forceinline__ int block_excl_scan_256(int v, int tid) {
    int lane = tid & 63, w = tid >> 6;
    int x = v;
#pragma unroll
    for (int off = 1; off < 64; off <<= 1) {
        int y = __shfl_up(x, off);
        if (lane >= off) x += y;
    }
    __shared__ int wsum[4], woff[4];
    if (lane == 63) wsum[w] = x;
    __syncthreads();
    if (tid == 0) {
        int a = 0;
#pragma unroll
        for (int i = 0; i < 4; ++i) { woff[i] = a; a += wsum[i]; }
    }
    __syncthreads();
    return woff[w] + x - v;
}

__global__ void scan_phase1(const int* __restrict__ deg,
                            int* __restrict__ partial, int n) {
    int base = blockIdx.x * 1024;
    int s = 0;
    for (int i = threadIdx.x; i < 1024; i += 256) {
        int idx = base + i;
        s += (idx < n) ? deg[idx] : 0;
    }
    __shared__ int ws4[4];
    int lane = threadIdx.x & 63, w = threadIdx.x >> 6;
#pragma unroll
    for (int off = 32; off; off >>= 1) s += __shfl_down(s, off);
    if (lane == 0) ws4[w] = s;
    __syncthreads();
    if (threadIdx.x == 0)
        partial[blockIdx.x] = ws4[0] + ws4[1] + ws4[2] + ws4[3];
}

__global__ void scan_phase2(int* __restrict__ partial, int nb,
                            int* __restrict__ rowptr, int n, int E) {
    int tid = threadIdx.x;
    int v = (tid < nb) ? partial[tid] : 0;
    int ex = block_excl_scan_256(v, tid);
    if (tid < nb) partial[tid] = ex;
    if (tid == 0) rowptr[n] = E;
}

__global__ void scan_phase3(const int* __restrict__ deg,
                            const int* __restrict__ partial,
                            int* __restrict__ rowptr, int* __restrict__ cursor,
                            float* __restrict__ inv_deg, int n) {
    int base = blockIdx.x * 1024 + threadIdx.x * 4;
    int d[4];
#pragma unroll
    for (int j = 0; j < 4; ++j) {
        int idx = base + j;
        d[j] = (idx < n) ? deg[idx] : 0;
    }
    int tsum = d[0] + d[1] + d[2] + d[3];
    int ex = block_excl_scan_256(tsum, threadIdx.x);
    int run = partial[blockIdx.x] + ex;
#pragma unroll
    for (int j = 0; j < 4; ++j) {
        int idx = base + j;
        if (idx < n) {
            rowptr[idx] = run;
            cursor[idx] = run;
            inv_deg[idx] = 1.0f / (float)max(d[j], 1);
        }
        run += d[j];
    }
}

// XCD-partitioned fill: dst range g = bid&7 (round-robin -> XCD g).
__global__ void fill_csr_xcd_kernel(const int* __restrict__ src,
                                    const int* __restrict__ dst,
                                    int* __restrict__ cursor,
                                    int* __restrict__ csr_src, int E, int n) {
    const int g = blockIdx.x & 7;
    const int lo = g * (n >> 3);
    const int hi = (g == 7) ? n : lo + (n >> 3);
    int i = ((blockIdx.x >> 3) * 256 + threadIdx.x) * 2;
    if (i + 1 < E) {
        int2 d = *(const int2*)&dst[i];
        if ((d.x >= lo && d.x < hi) || (d.y >= lo && d.y < hi)) {
            int2 s = *(const int2*)&src[i];
            if (d.x >= lo && d.x < hi) {
                int p = atomicAdd(&cursor[d.x], 1);
                csr_src[p] = s.x;
            }
            if (d.y >= lo && d.y < hi) {
                int p = atomicAdd(&cursor[d.y], 1);
                csr_src[p] = s.y;
            }
        }
    } else if (i < E) {
        int d = dst[i];
        if (d >= lo && d < hi) {
            int p = atomicAdd(&cursor[d], 1);
            csr_src[p] = src[i];
        }
    }
}

// ----------------- W -> fp16 fragment order (+ zero deg) -------------------
// per (layer,source): [k0chunk(8)][tile(16)][g(4)][col(16)][j(8)]
__global__ void presplit_w_kernel(const float* __restrict__ Wl,
                                  const float* __restrict__ Wr,
                                  _Float16* __restrict__ Wf,
                                  int* __restrict__ deg, int N, int total) {
    int idx = blockIdx.x * blockDim.x + threadIdx.x;
    if (idx < N) deg[idx] = 0;
    if (idx >= total) return;
    int l = idx >> 17;
    int rem = idx & 131071;
    int s = rem >> 16;
    int kc = rem & 65535;
    int k = kc >> 8, c = kc & 255;
    const float* W = s ? Wr : Wl;
    float w = W[((size_t)l * 256 + k) * 256 + c];
    int k0c = k >> 5, g = (k >> 3) & 3, j = k & 7;
    int tile = c >> 4, col = c & 15;
    int fi = (l * 2 + s) * 65536 + k0c * 8192 + ((tile * 4 + g) * 16 + col) * 8 + j;
    Wf[fi] = (_Float16)w;
}

// --------------------------- dual GEMM (fp32 or fp16 A) --------------------
// 64-row block, 8 waves: wave w -> ALL 64 rows x cols w*32..w*32+31
// (4 row-tiles x 2 col-tiles). W prefetched TWO k0-steps ahead (3-buffer
// static rotation; fully unrolled so all indices are compile-time).
// A: x fp32 row-major (layer 0) or h fp16 panel-major [8][M][32].
// OUTPUT PANEL-MAJOR: z[p][row][off], p=col>>5.
__global__ __launch_bounds__(512) void gemm_dual_kernel(
    const float* __restrict__ xsrc, const _Float16* __restrict__ hsrc,
    int f32src, _Float16* __restrict__ zl, _Float16* __restrict__ zr,
    const _Float16* __restrict__ Wf_l, const float* __restrict__ bias, int M) {
    __shared__ __align__(16) _Float16 Ah[32][65][8];
    const int tid = threadIdx.x;
    const int r0 = blockIdx.x * 64;
    const int wave = tid >> 6, lane = tid & 63;
    const int l15 = lane & 15, lg = lane >> 4;
    const int wc = wave * 32;
    const int tg0 = wc >> 4;               // = wave*2
    const _Float16* wbase = Wf_l + (lg * 16 + l15) * 8;

    // steps 0 and 1 W prefetch BEFORE staging (latency hides under LDS fill)
    f16x8 wl[3][2], wr[3][2];
#pragma unroll
    for (int s = 0; s < 2; ++s)
#pragma unroll
        for (int t = 0; t < 2; ++t) {
            wl[s][t] = *(const f16x8*)&wbase[s * 8192 + (tg0 + t) * 512];
            wr[s][t] = *(const f16x8*)&wbase[s * 8192 + 65536 + (tg0 + t) * 512];
        }

    // ---- stage A stripe (64x256) ----
#pragma unroll
    for (int i = 0; i < 4; ++i) {
        int idx = i * 512 + tid;        // 0..2047
        int row = idx >> 5, g = idx & 31;
        int grow = r0 + row;
        f16x8 v = (f16x8)(_Float16)0;
        if (grow < M) {
            if (f32src) {
                const float4* p =
                    (const float4*)&xsrc[(size_t)grow * 256 + g * 8];
                float4 v0 = p[0], v1 = p[1];
                v[0] = (_Float16)v0.x; v[1] = (_Float16)v0.y;
                v[2] = (_Float16)v0.z; v[3] = (_Float16)v0.w;
                v[4] = (_Float16)v1.x; v[5] = (_Float16)v1.y;
                v[6] = (_Float16)v1.z; v[7] = (_Float16)v1.w;
            } else {
                int p = g >> 2, off = (g & 3) * 8;   // panel-major h
                v = *(const f16x8*)&hsrc[((size_t)p * M + grow) * 32 + off];
            }
        }
        *(f16x8*)&Ah[g][row][0] = v;
    }
    __syncthreads();

    // ---- MFMA main loop (W prefetched two steps ahead) ----
    f32x4 accl[4][2], accr[4][2];
#pragma unroll
    for (int rt = 0; rt < 4; ++rt)
#pragma unroll
        for (int t = 0; t < 2; ++t) {
            accl[rt][t] = (f32x4)(0.0f);
            accr[rt][t] = (f32x4)(0.0f);
        }

#pragma unroll
    for (int s = 0; s < 8; ++s) {
        if (s < 6) {
            const _Float16* wn = wbase + (s + 2) * 8192;
#pragma unroll
            for (int t = 0; t < 2; ++t) {
                wl[(s + 2) % 3][t] = *(const f16x8*)&wn[(tg0 + t) * 512];
                wr[(s + 2) % 3][t] =
                    *(const f16x8*)&wn[65536 + (tg0 + t) * 512];
            }
        }
        f16x8 a[4];
#pragma unroll
        for (int rt = 0; rt < 4; ++rt)
            a[rt] = *(const f16x8*)&Ah[s * 4 + lg][rt * 16 + l15][0];
#pragma unroll
        for (int t = 0; t < 2; ++t) {
#pragma unroll
            for (int rt = 0; rt < 4; ++rt) {
                accl[rt][t] = __builtin_amdgcn_mfma_f32_16x16x32_f16(
                    a[rt], wl[s % 3][t], accl[rt][t], 0, 0, 0);
                accr[rt][t] = __builtin_amdgcn_mfma_f32_16x16x32_f16(
                    a[rt], wr[s % 3][t], accr[rt][t], 0, 0, 0);
            }
        }
    }

    float bv[2];
#pragma unroll
    for (int t = 0; t < 2; ++t) bv[t] = bias[wc + t * 16 + l15];
#pragma unroll
    for (int rt = 0; rt < 4; ++rt) {
#pragma unroll
        for (int r = 0; r < 4; ++r) {
            int grow = r0 + rt * 16 + lg * 4 + r;
            if (grow >= M) continue;
#pragma unroll
            for (int t = 0; t < 2; ++t) {
                int col = wc + t * 16 + l15;
                int p = col >> 5, off = col & 31;
                size_t zi = ((size_t)p * M + grow) * 32 + off;
                zl[zi] = (_Float16)accl[rt][t][r];
                zr[zi] = (_Float16)(accr[rt][t][r] + bv[t]);
            }
        }
    }
}

// ------------------- panel-major sliced combine (8-lane groups) ------------
// grid = 8 slices x ceil(n/32); slice = bid&7 -> XCD bid%8 (panel in L2).
// 8 lanes per node: two 4-lane halves take alternating 8-edge bursts.
// Gathers use block-uniform SGPR base + 32-bit byte offsets (saddr form);
// csr indices software-pipelined one trip ahead. Dual-chain packed fp16
// accumulation; clamped duplicates corrected by closed-form subtract.
// mode 0: relu -> fp16 PANEL-MAJOR h. mode 1: fp32 row-major out.
__global__ __launch_bounds__(256) void combine_panel_kernel(
    const _Float16* __restrict__ zl, const _Float16* __restrict__ zr,
    const int* __restrict__ rowptr, const int* __restrict__ csr_src,
    const float* __restrict__ inv_deg, _Float16* __restrict__ hout,
    float* __restrict__ fout, int n, int mode) {
    const int slice = blockIdx.x & 7;
    const int chunk = blockIdx.x >> 3;
    const int grp = threadIdx.x >> 3;     // 0..31
    const int sub = threadIdx.x & 7;
    const int pair = sub >> 2;            // 0 or 1
    const int l4 = sub & 3;
    // block-uniform bases (SGPR); per-lane 32-bit byte offsets
    const char* zl_s = (const char*)(zl + (size_t)slice * n * 32);
    const char* zr_s = (const char*)(zr + (size_t)slice * n * 32);
    const unsigned lb = (unsigned)l4 * 16;

    int v = chunk * 32 + grp;
    if (v >= n) return;
    int beg = rowptr[v], end = rowptr[v + 1];
    float sc = inv_deg[v];
    // hoist independent own-node loads ahead of the gather loop
    f16x8 zp = *(const f16x8*)(zr_s + (((unsigned)v << 6) + lb));
    float o[8];
    if (beg < end) {
        f16x8 acc0 = (f16x8)(_Float16)0, acc1 = (f16x8)(_Float16)0;
        int u[8];
#pragma unroll
        for (int k = 0; k < 8; ++k)
            u[k] = csr_src[min(beg + pair * 8 + k, end - 1)];
        for (int e = beg; e < end; e += 16) {
            f16x8 t[8];
#pragma unroll
            for (int k = 0; k < 8; ++k)
                t[k] = *(const f16x8*)(zl_s + (((unsigned)u[k] << 6) + lb));
            int e2 = e + 16;
            if (e2 < end) {
#pragma unroll
                for (int k = 0; k < 8; ++k)
                    u[k] = csr_src[min(e2 + pair * 8 + k, end - 1)];
            }
#pragma unroll
            for (int k = 0; k < 4; ++k) {
                acc0 += t[k];              // v_pk_add_f16, two chains for ILP
                acc1 += t[k + 4];
            }
        }
        // overcount fixup: last trip's clamped duplicates of edge end-1
        int d = end - beg;
        int T = (d + 15) >> 4;
        int rem = d - ((T - 1) << 4);                 // 1..16
        int valid = pair ? max(rem - 8, 0) : min(rem, 8);
        float inval = (float)(8 - valid);
        int ulast = csr_src[end - 1];
        f16x8 tl = *(const f16x8*)(zl_s + (((unsigned)ulast << 6) + lb));
#pragma unroll
        for (int j = 0; j < 8; ++j)
            o[j] = (float)acc0[j] + (float)acc1[j] - inval * (float)tl[j];
    } else {
#pragma unroll
        for (int j = 0; j < 8; ++j) o[j] = 0.0f;
    }
#pragma unroll
    for (int j = 0; j < 8; ++j) o[j] += __shfl_xor(o[j], 4);
    if (pair == 0) {
#pragma unroll
        for (int j = 0; j < 8; ++j) o[j] = o[j] * sc + (float)zp[j];
        if (mode == 0) {
            f16x8 hv;
#pragma unroll
            for (int j = 0; j < 8; ++j) hv[j] = (_Float16)fmaxf(o[j], 0.0f);
            *(f16x8*)&hout[((size_t)slice * n + v) * 32 + l4 * 8] = hv;
        } else {
            int cbase = slice * 32 + l4 * 8;
            float4* op = (float4*)&fout[(size_t)v * 256 + cbase];
            op[0] = make_float4(o[0], o[1], o[2], o[3]);
            op[1] = make_float4(o[4], o[5], o[6], o[7]);
        }
    }
}

// --------------------------------- launch ---------------------------------
extern "C" void kernel_launch(void* const* d_in, const int* in_sizes, int n_in,
                              void* d_out, int out_size, void* d_ws, size_t ws_size,
                              hipStream_t stream) {
    const int D = 256;
    const int N = in_sizes[0] / D;
    const int E = in_sizes[1] / 2;
    const int L = in_sizes[2] / (D * D);

    const float* x  = (const float*)d_in[0];
    const int*   ei = (const int*)d_in[1];
    const float* Wl = (const float*)d_in[2];
    const float* Wr = (const float*)d_in[3];
    const float* b  = (const float*)d_in[4];
    const int* src = ei;
    const int* dst = ei + E;

    size_t off = 0;
    auto alloc = [&](size_t bytes) {
        void* p = (char*)d_ws + off;
        off += (bytes + 255) & ~(size_t)255;
        return p;
    };
    int*   deg     = (int*)alloc((size_t)N * 4);
    int*   rowptr  = (int*)alloc((size_t)(N + 1) * 4);
    int*   cursor  = (int*)alloc((size_t)N * 4);
    float* inv_deg = (float*)alloc((size_t)N * 4);
    int*   csr_src = (int*)alloc((size_t)E * 4);
    int*   partial = (int*)alloc(256 * 4);
    _Float16* zlP  = (_Float16*)alloc((size_t)N * D * 2);  // pair P (panel-major)
    _Float16* zrP  = (_Float16*)alloc((size_t)N * D * 2);
    _Float16* hbuf = (_Float16*)alloc((size_t)N * D * 2);  // h (panel-major)
    _Float16* Wf   = (_Float16*)alloc((size_t)L * 2 * 65536 * 2);
    (void)ws_size;

    // pair Q packed into d_out (panel-major fp16); C2 overwrites with fp32
    _Float16* zlQ = (_Float16*)d_out;
    _Float16* zrQ = zlQ + (size_t)N * D;
    float* outf = (float*)d_out;

    const int scan_blocks = (N + 1023) / 1024;

    // W -> fp16 fragment order (also zeroes deg)
    int wtotal = L * 2 * 65536;
    hipLaunchKernelGGL(presplit_w_kernel, dim3((wtotal + 255) / 256), dim3(256),
                       0, stream, Wl, Wr, Wf, deg, N, wtotal);

    // CSR build
    hipLaunchKernelGGL(count_deg_kernel, dim3((E / 2 + 255) / 256), dim3(256),
                       0, stream, dst, deg, E);
    hipLaunchKernelGGL(scan_phase1, dim3(scan_blocks), dim3(256), 0, stream,
                       deg, partial, N);
    hipLaunchKernelGGL(scan_phase2, dim3(1), dim3(256), 0, stream,
                       partial, scan_blocks, rowptr, N, E);
    hipLaunchKernelGGL(scan_phase3, dim3(scan_blocks), dim3(256), 0, stream,
                       deg, partial, rowptr, cursor, inv_deg, N);
    const int fill_chunks = (E / 2 + 255) / 256;
    hipLaunchKernelGGL(fill_csr_xcd_kernel, dim3(8 * fill_chunks), dim3(256),
                       0, stream, src, dst, cursor, csr_src, E, N);

    const int gemm_blocks = (N + 63) / 64;
    const int comb_blocks = 8 * ((N + 31) / 32);

    // L0: x -> P ; combine P -> h
    hipLaunchKernelGGL(gemm_dual_kernel, dim3(gemm_blocks), dim3(512), 0,
                       stream, x, (const _Float16*)nullptr, 1, zlP, zrP,
                       Wf, b, N);
    hipLaunchKernelGGL(combine_panel_kernel, dim3(comb_blocks), dim3(256), 0,
                       stream, zlP, zrP, rowptr, csr_src, inv_deg,
                       hbuf, outf, N, 0);
    // L1: h -> Q (d_out) ; combine Q -> h
    hipLaunchKernelGGL(gemm_dual_kernel, dim3(gemm_blocks), dim3(512), 0,
                       stream, (const float*)nullptr, hbuf, 0, zlQ, zrQ,
                       Wf + 131072, b + D, N);
    hipLaunchKernelGGL(combine_panel_kernel, dim3(comb_blocks), dim3(256), 0,
                       stream, zlQ, zrQ, rowptr, csr_src, inv_deg,
                       hbuf, outf, N, 0);
    // L2: h -> P ; final combine P -> d_out fp32
    hipLaunchKernelGGL(gemm_dual_kernel, dim3(gemm_blocks), dim3(512), 0,
                       stream, (const float*)nullptr, hbuf, 0, zlP, zrP,
                       Wf + 262144, b + 2 * D, N);
    hipLaunchKernelGGL(combine_panel_kernel, dim3(comb_blocks), dim3(256), 0,
                       stream, zlP, zrP, rowptr, csr_src, inv_deg,
                       hbuf, outf, N, 1);
}